// Round 3
// baseline (732.558 us; speedup 1.0000x reference)
//
#include <hip/hip_runtime.h>
#include <hip/hip_bf16.h>

// GCN encoder: x = emb[types]; x1 = relu(gcnconv(x,W1,b1)); out = gcnconv(x1,W2,b2)
// gcnconv: deg[i] = indeg(i)+1 (self loop); dis = rsqrt(deg);
//          out[i] = sum_{e:dst=i} (x[src_e]@W)*dis[src]*dis[i] + (x[i]@W)*dis[i]^2 + b
//
// Strategy:
//  - embW = emb @ W1  (1000x128, L2-resident) so layer-1 messages gather from 512KB.
//  - CSR by dst (histogram + scan + fill) -> per-node wave gather, no f32 atomics.
//  - agg1 FUSES the layer-2 GEMM: after the wave computes the x1 row in registers,
//    it immediately computes h2 row = relu(x1)@W2 via readlane broadcast + LDS W2
//    (transposed, XOR-swizzled for b128 reads). x1 is never materialized.
//  - agg2 gathers 256B h2 rows -> out.

#define D1 128
#define D2 64

__global__ void count_k(const int* __restrict__ dst, int* __restrict__ cnt, int e) {
    int stride = gridDim.x * blockDim.x;
    for (int t = blockIdx.x * blockDim.x + threadIdx.x; t < e; t += stride)
        atomicAdd(&cnt[dst[t]], 1);
}

__global__ void dis_k(const int* __restrict__ cnt, float* __restrict__ dis, int n) {
    int stride = gridDim.x * blockDim.x;
    for (int t = blockIdx.x * blockDim.x + threadIdx.x; t < n; t += stride)
        dis[t] = rsqrtf((float)(cnt[t] + 1));
}

// ---- 3-kernel exclusive scan of cnt[] -> off[] ----
__global__ void scan1_k(const int* __restrict__ cnt, int* __restrict__ off,
                        int* __restrict__ bsum, int n) {
    __shared__ int tmp[256];
    int tid = threadIdx.x;
    int gid = blockIdx.x * 256 + tid;
    int v = (gid < n) ? cnt[gid] : 0;
    tmp[tid] = v;
    __syncthreads();
    for (int s = 1; s < 256; s <<= 1) {
        int a = (tid >= s) ? tmp[tid - s] : 0;
        __syncthreads();
        tmp[tid] += a;
        __syncthreads();
    }
    if (gid < n) off[gid] = tmp[tid] - v;           // exclusive
    if (tid == 255) bsum[blockIdx.x] = tmp[255];    // block total
}

__global__ void scan2_k(int* __restrict__ bsum, int nb) {
    __shared__ int tmp[1024];
    int tid = threadIdx.x;
    int v = (tid < nb) ? bsum[tid] : 0;
    tmp[tid] = v;
    __syncthreads();
    for (int s = 1; s < 1024; s <<= 1) {
        int a = (tid >= s) ? tmp[tid - s] : 0;
        __syncthreads();
        tmp[tid] += a;
        __syncthreads();
    }
    if (tid < nb) bsum[tid] = tmp[tid] - v;         // exclusive over blocks
}

__global__ void scan3_k(int* __restrict__ off, const int* __restrict__ bsum, int n) {
    int gid = blockIdx.x * 256 + threadIdx.x;
    if (gid < n) off[gid] += bsum[blockIdx.x];
}

__global__ void fill_k(const int* __restrict__ src, const int* __restrict__ dst,
                       const int* __restrict__ off, int* __restrict__ cursor,
                       int* __restrict__ csr_src, int e) {
    int stride = gridDim.x * blockDim.x;
    for (int t = blockIdx.x * blockDim.x + threadIdx.x; t < e; t += stride) {
        int d = dst[t];
        int p = off[d] + atomicAdd(&cursor[d], 1);
        csr_src[p] = src[t];
    }
}

// embW[r][j] = sum_k emb[r][k] * W1[k][j]   (ntypes x 128)
__global__ __launch_bounds__(128) void gemm_emb_k(const float* __restrict__ emb,
                                                  const float* __restrict__ W1,
                                                  float* __restrict__ embW, int ntypes) {
    __shared__ float w[D1 * D1];  // 64 KB
    for (int t = threadIdx.x; t < D1 * D1; t += 128) w[t] = W1[t];
    __syncthreads();
    int j = threadIdx.x;
    for (int r = blockIdx.x; r < ntypes; r += gridDim.x) {
        const float* er = emb + (size_t)r * D1;
        float acc = 0.f;
        #pragma unroll 8
        for (int k = 0; k < D1; ++k) acc = fmaf(er[k], w[k * D1 + j], acc);
        embW[(size_t)r * D1 + j] = acc;
    }
}

// layer-1 aggregation + fused layer-2 GEMM.
// One wave per node. Edge loop: 2 sub-groups of 32 lanes, each handles one edge
// per iteration, lane holds float4 at feature (lane&31)*4. After xor-32 reduce
// every lane has the full x1 row; epilogue computes h2[i][lane] directly.
// W2 staged in LDS transposed: row j (=lane) holds the 32 float4 k-groups of
// column j, group k4 stored at slot (k4 ^ (j&7)) so a wave-wide ds_read_b128
// at equal k4 spreads over all 32 banks.
__global__ __launch_bounds__(256, 4) void agg1h2_k(const int* __restrict__ types,
                                                   const int* __restrict__ csr_src,
                                                   const int* __restrict__ off,
                                                   const int* __restrict__ cnt,
                                                   const float* __restrict__ dis,
                                                   const float* __restrict__ embW,
                                                   const float* __restrict__ b1,
                                                   const float* __restrict__ W2,
                                                   float* __restrict__ h2, int n) {
    __shared__ float w2t[D2 * D1];  // 32 KB: [j][swizzled 4-float k-groups]
    // coalesced global read of W2 (row-major [k][j]), scattered LDS transpose
    for (int t = threadIdx.x; t < (D1 / 4) * (D2 / 4) * 4; t += 256) {
        // t enumerates (k, j4): k = t>>4 in steps below, 4 columns per thread
        int k = t >> 4;          // 0..127 over 8 iterations (t < 2048)
        int j4 = (t & 15) << 2;  // 0,4,...,60
        float4 v = *(const float4*)(W2 + (size_t)k * D2 + j4);
        int k4 = k >> 2, kc = k & 3;
        float vv[4] = {v.x, v.y, v.z, v.w};
        #pragma unroll
        for (int c = 0; c < 4; ++c) {
            int j = j4 + c;
            w2t[j * D1 + ((k4 ^ (j & 7)) << 2) + kc] = vv[c];
        }
    }
    __syncthreads();
    const float4* w2v = (const float4*)w2t;

    int wid = (blockIdx.x * blockDim.x + threadIdx.x) >> 6;
    int lane = threadIdx.x & 63;
    int nwaves = (gridDim.x * blockDim.x) >> 6;
    int sub = lane >> 5;            // 0..1
    int fl = (lane & 31) << 2;      // feature base 0..124
    int lbase = lane << 5;          // float4 row base in w2t
    int lx = lane & 7;              // swizzle key
    for (int i = wid; i < n; i += nwaves) {
        float disi = dis[i];
        int base = off[i], c = cnt[i];
        int total = c + 1;          // + self loop
        float4 acc = make_float4(0.f, 0.f, 0.f, 0.f);
        for (int cb = 0; cb < total; cb += 64) {
            // lane-parallel preload of (type, coef) for edges cb..cb+63
            int idx = cb + lane;
            int s_l = i;
            float c_l = 0.f;
            if (idx < c) {
                s_l = csr_src[base + idx];
                c_l = disi * dis[s_l];
            } else if (idx == c) {
                c_l = disi * disi;  // self loop
            }
            int t_l = types[s_l];
            int m = min(64, total - cb);
            for (int k0 = 0; k0 < m; k0 += 2) {
                int k = k0 + sub;   // <= 63 always
                int t = __shfl(t_l, k);
                float cf = __shfl(c_l, k);  // 0 for out-of-range k
                float4 v = *(const float4*)(embW + (size_t)t * D1 + fl);
                acc.x = fmaf(v.x, cf, acc.x);
                acc.y = fmaf(v.y, cf, acc.y);
                acc.z = fmaf(v.z, cf, acc.z);
                acc.w = fmaf(v.w, cf, acc.w);
            }
        }
        // reduce the two sub-groups -> every lane holds the full row sum
        acc.x += __shfl_xor(acc.x, 32);
        acc.y += __shfl_xor(acc.y, 32);
        acc.z += __shfl_xor(acc.z, 32);
        acc.w += __shfl_xor(acc.w, 32);
        // bias + relu (x1 row now lives in-register across lanes 0..31, mirrored)
        float4 bv = ((const float4*)b1)[lane & 31];
        acc.x = fmaxf(acc.x + bv.x, 0.f);
        acc.y = fmaxf(acc.y + bv.y, 0.f);
        acc.z = fmaxf(acc.z + bv.z, 0.f);
        acc.w = fmaxf(acc.w + bv.w, 0.f);
        // fused GEMM epilogue: h2[i][lane] = sum_k x1[k] * W2[k][lane]
        float h0 = 0.f, h1 = 0.f;
        #pragma unroll
        for (int k4 = 0; k4 < 32; k4 += 2) {
            float4 wv0 = w2v[lbase + (k4 ^ lx)];
            h0 = fmaf(__shfl(acc.x, k4), wv0.x, h0);
            h0 = fmaf(__shfl(acc.y, k4), wv0.y, h0);
            h0 = fmaf(__shfl(acc.z, k4), wv0.z, h0);
            h0 = fmaf(__shfl(acc.w, k4), wv0.w, h0);
            float4 wv1 = w2v[lbase + ((k4 + 1) ^ lx)];
            h1 = fmaf(__shfl(acc.x, k4 + 1), wv1.x, h1);
            h1 = fmaf(__shfl(acc.y, k4 + 1), wv1.y, h1);
            h1 = fmaf(__shfl(acc.z, k4 + 1), wv1.z, h1);
            h1 = fmaf(__shfl(acc.w, k4 + 1), wv1.w, h1);
        }
        h2[(size_t)i * D2 + lane] = h0 + h1;
    }
}

// layer-2 aggregation: one wave per node. 4 sub-groups of 16 lanes; each sub
// handles one edge per iteration, lane holds float4 at feature (lane&15)*4.
__global__ __launch_bounds__(256) void agg2_k(const int* __restrict__ csr_src,
                                              const int* __restrict__ off,
                                              const int* __restrict__ cnt,
                                              const float* __restrict__ dis,
                                              const float* __restrict__ h2,
                                              const float* __restrict__ b2,
                                              float* __restrict__ out, int n) {
    int wid = (blockIdx.x * blockDim.x + threadIdx.x) >> 6;
    int lane = threadIdx.x & 63;
    int nwaves = (gridDim.x * blockDim.x) >> 6;
    int sub = lane >> 4;            // 0..3
    int fl = (lane & 15) << 2;      // feature base 0..60
    for (int i = wid; i < n; i += nwaves) {
        float disi = dis[i];
        int base = off[i], c = cnt[i];
        int total = c + 1;          // + self loop
        float4 acc = make_float4(0.f, 0.f, 0.f, 0.f);
        for (int cb = 0; cb < total; cb += 64) {
            int idx = cb + lane;
            int s_l = i;
            float c_l = 0.f;
            if (idx < c) {
                s_l = csr_src[base + idx];
                c_l = disi * dis[s_l];
            } else if (idx == c) {
                c_l = disi * disi;  // self loop
            }
            int m = min(64, total - cb);
            for (int k0 = 0; k0 < m; k0 += 4) {
                int k = k0 + sub;   // <= 63 always
                int s = __shfl(s_l, k);
                float cf = __shfl(c_l, k);  // 0 for out-of-range k
                float4 v = *(const float4*)(h2 + (size_t)s * D2 + fl);
                acc.x = fmaf(v.x, cf, acc.x);
                acc.y = fmaf(v.y, cf, acc.y);
                acc.z = fmaf(v.z, cf, acc.z);
                acc.w = fmaf(v.w, cf, acc.w);
            }
        }
        // reduce the four sub-groups
        acc.x += __shfl_xor(acc.x, 16);
        acc.y += __shfl_xor(acc.y, 16);
        acc.z += __shfl_xor(acc.z, 16);
        acc.w += __shfl_xor(acc.w, 16);
        acc.x += __shfl_xor(acc.x, 32);
        acc.y += __shfl_xor(acc.y, 32);
        acc.z += __shfl_xor(acc.z, 32);
        acc.w += __shfl_xor(acc.w, 32);
        if (sub == 0) {
            float4 bv = ((const float4*)b2)[lane & 15];
            acc.x += bv.x;
            acc.y += bv.y;
            acc.z += bv.z;
            acc.w += bv.w;
            ((float4*)(out + (size_t)i * D2))[lane & 15] = acc;
        }
    }
}

extern "C" void kernel_launch(void* const* d_in, const int* in_sizes, int n_in,
                              void* d_out, int out_size, void* d_ws, size_t ws_size,
                              hipStream_t stream) {
    const int* types = (const int*)d_in[0];
    const int* edges = (const int*)d_in[1];
    const float* emb = (const float*)d_in[2];
    const float* W1  = (const float*)d_in[3];
    const float* b1  = (const float*)d_in[4];
    const float* W2  = (const float*)d_in[5];
    const float* b2  = (const float*)d_in[6];
    float* out = (float*)d_out;

    const int n = in_sizes[0];
    const int e = in_sizes[1] / 2;
    const int ntypes = in_sizes[2] / D1;
    const int* src = edges;
    const int* dst = edges + e;

    // ---- workspace layout (256B aligned slabs) ----
    char* p = (char*)d_ws;
    auto alloc = [&](size_t bytes) {
        char* r = p;
        p += (bytes + 255) & ~(size_t)255;
        return r;
    };
    int*   off     = (int*)  alloc((size_t)(n + 1) * 4);
    int*   cnt     = (int*)  alloc((size_t)n * 4);
    int*   cursor  = (int*)  alloc((size_t)n * 4);
    int*   bsum    = (int*)  alloc(1024 * 4);
    float* dis     = (float*)alloc((size_t)n * 4);
    int*   csr_src = (int*)  alloc((size_t)e * 4);
    float* embW    = (float*)alloc((size_t)ntypes * D1 * 4);
    float* h2      = (float*)alloc((size_t)n * D2 * 4);
    (void)ws_size;

    hipMemsetAsync(cnt, 0, (size_t)n * 4, stream);
    hipMemsetAsync(cursor, 0, (size_t)n * 4, stream);

    // ---- degree / dis / CSR ----
    count_k<<<2048, 256, 0, stream>>>(dst, cnt, e);
    dis_k<<<(n + 255) / 256, 256, 0, stream>>>(cnt, dis, n);
    int nb = (n + 255) / 256;   // 391 for N=100000 (must be <= 1024)
    scan1_k<<<nb, 256, 0, stream>>>(cnt, off, bsum, n);
    scan2_k<<<1, 1024, 0, stream>>>(bsum, nb);
    scan3_k<<<nb, 256, 0, stream>>>(off, bsum, n);
    fill_k<<<2048, 256, 0, stream>>>(src, dst, off, cursor, csr_src, e);

    // ---- layer 1: embW = emb@W1; aggregate + fused layer-2 GEMM -> h2 ----
    gemm_emb_k<<<256, 128, 0, stream>>>(emb, W1, embW, ntypes);
    agg1h2_k<<<2048, 256, 0, stream>>>(types, csr_src, off, cnt, dis, embW, b1, W2, h2, n);

    // ---- layer 2: aggregate h2 -> out ----
    agg2_k<<<2048, 256, 0, stream>>>(csr_src, off, cnt, dis, h2, b2, out, n);
}

// Round 4
// 483.425 us; speedup vs baseline: 1.5153x; 1.5153x over previous
//
#include <hip/hip_runtime.h>
#include <hip/hip_bf16.h>

// GCN encoder: x = emb[types]; x1 = relu(gcnconv(x,W1,b1)); out = gcnconv(x1,W2,b2)
// gcnconv: deg[i] = indeg(i)+1 (self loop); dis = rsqrt(deg);
//          out[i] = sum_{e:dst=i} (x[src_e]@W)*dis[src]*dis[i] + (x[i]@W)*dis[i]^2 + b
//
// Strategy (round 4):
//  - embW = emb @ W1 (1000x128, L2-resident): layer-1 messages gather 512B rows.
//  - CSR by dst; fill_k precomputes per-edge {src, type[src], dis[src]} so the
//    agg kernels read coalesced streams instead of chasing 3-hop gather chains.
//  - agg kernels: one wave per node, zero LDS, max occupancy (latency-bound).
//  - gemm2: h2 = x1@W2 written IN-PLACE into x1 rows (cols 0..63); low VGPR.

#define D1 128
#define D2 64

__global__ void count_k(const int* __restrict__ dst, int* __restrict__ cnt, int e) {
    int stride = gridDim.x * blockDim.x;
    for (int t = blockIdx.x * blockDim.x + threadIdx.x; t < e; t += stride)
        atomicAdd(&cnt[dst[t]], 1);
}

__global__ void dis_k(const int* __restrict__ cnt, float* __restrict__ dis, int n) {
    int stride = gridDim.x * blockDim.x;
    for (int t = blockIdx.x * blockDim.x + threadIdx.x; t < n; t += stride)
        dis[t] = rsqrtf((float)(cnt[t] + 1));
}

// ---- 3-kernel exclusive scan of cnt[] -> off[] ----
__global__ void scan1_k(const int* __restrict__ cnt, int* __restrict__ off,
                        int* __restrict__ bsum, int n) {
    __shared__ int tmp[256];
    int tid = threadIdx.x;
    int gid = blockIdx.x * 256 + tid;
    int v = (gid < n) ? cnt[gid] : 0;
    tmp[tid] = v;
    __syncthreads();
    for (int s = 1; s < 256; s <<= 1) {
        int a = (tid >= s) ? tmp[tid - s] : 0;
        __syncthreads();
        tmp[tid] += a;
        __syncthreads();
    }
    if (gid < n) off[gid] = tmp[tid] - v;           // exclusive
    if (tid == 255) bsum[blockIdx.x] = tmp[255];    // block total
}

__global__ void scan2_k(int* __restrict__ bsum, int nb) {
    __shared__ int tmp[1024];
    int tid = threadIdx.x;
    int v = (tid < nb) ? bsum[tid] : 0;
    tmp[tid] = v;
    __syncthreads();
    for (int s = 1; s < 1024; s <<= 1) {
        int a = (tid >= s) ? tmp[tid - s] : 0;
        __syncthreads();
        tmp[tid] += a;
        __syncthreads();
    }
    if (tid < nb) bsum[tid] = tmp[tid] - v;         // exclusive over blocks
}

__global__ void scan3_k(int* __restrict__ off, const int* __restrict__ bsum, int n) {
    int gid = blockIdx.x * 256 + threadIdx.x;
    if (gid < n) off[gid] += bsum[blockIdx.x];
}

// fill CSR + precompute per-edge type/dis payloads
__global__ void fill_k(const int* __restrict__ src, const int* __restrict__ dst,
                       const int* __restrict__ types, const float* __restrict__ dis,
                       const int* __restrict__ off, int* __restrict__ cursor,
                       int* __restrict__ csr_src, int* __restrict__ csr_type,
                       float* __restrict__ csr_dis, int e) {
    int stride = gridDim.x * blockDim.x;
    for (int t = blockIdx.x * blockDim.x + threadIdx.x; t < e; t += stride) {
        int d = dst[t];
        int s = src[t];
        int p = off[d] + atomicAdd(&cursor[d], 1);
        csr_src[p] = s;
        csr_type[p] = types[s];
        csr_dis[p] = dis[s];
    }
}

// embW[r][j] = sum_k emb[r][k] * W1[k][j]   (ntypes x 128)
__global__ __launch_bounds__(128) void gemm_emb_k(const float* __restrict__ emb,
                                                  const float* __restrict__ W1,
                                                  float* __restrict__ embW, int ntypes) {
    __shared__ float w[D1 * D1];  // 64 KB
    for (int t = threadIdx.x; t < D1 * D1; t += 128) w[t] = W1[t];
    __syncthreads();
    int j = threadIdx.x;
    for (int r = blockIdx.x; r < ntypes; r += gridDim.x) {
        const float* er = emb + (size_t)r * D1;
        float acc = 0.f;
        #pragma unroll 8
        for (int k = 0; k < D1; ++k) acc = fmaf(er[k], w[k * D1 + j], acc);
        embW[(size_t)r * D1 + j] = acc;
    }
}

// layer-1 aggregation: ONE WAVE PER NODE. 2 sub-groups of 32 lanes; each sub
// handles one edge per iteration, lane holds float4 at feature (lane&31)*4.
__global__ __launch_bounds__(256) void agg1_k(const int* __restrict__ types,
                                              const int* __restrict__ csr_type,
                                              const float* __restrict__ csr_dis,
                                              const int* __restrict__ off,
                                              const int* __restrict__ cnt,
                                              const float* __restrict__ dis,
                                              const float* __restrict__ embW,
                                              const float* __restrict__ b1,
                                              float* __restrict__ x1, int n) {
    int i = (blockIdx.x * blockDim.x + threadIdx.x) >> 6;   // node = wave id
    if (i >= n) return;
    int lane = threadIdx.x & 63;
    int sub = lane >> 5;            // 0..1
    int fl = (lane & 31) << 2;      // feature base 0..124
    float disi = dis[i];
    int ti = types[i];
    int base = off[i], c = cnt[i];
    int total = c + 1;              // + self loop (virtual edge idx==c)
    float4 acc = make_float4(0.f, 0.f, 0.f, 0.f);
    for (int cb = 0; cb < total; cb += 64) {
        int idx = cb + lane;
        int t_l = 0;
        float c_l = 0.f;
        if (idx < c) {
            t_l = csr_type[base + idx];
            c_l = disi * csr_dis[base + idx];
        } else if (idx == c) {
            t_l = ti;
            c_l = disi * disi;      // self loop
        }
        int m = min(64, total - cb);
        for (int k0 = 0; k0 < m; k0 += 2) {
            int k = k0 + sub;       // <= 63 always
            int t = __shfl(t_l, k);
            float cf = __shfl(c_l, k);  // 0 for out-of-range k
            float4 v = *(const float4*)(embW + (size_t)t * D1 + fl);
            acc.x = fmaf(v.x, cf, acc.x);
            acc.y = fmaf(v.y, cf, acc.y);
            acc.z = fmaf(v.z, cf, acc.z);
            acc.w = fmaf(v.w, cf, acc.w);
        }
    }
    // reduce the two sub-groups
    acc.x += __shfl_xor(acc.x, 32);
    acc.y += __shfl_xor(acc.y, 32);
    acc.z += __shfl_xor(acc.z, 32);
    acc.w += __shfl_xor(acc.w, 32);
    if (sub == 0) {
        float4 bv = ((const float4*)b1)[lane & 31];
        acc.x = fmaxf(acc.x + bv.x, 0.f);
        acc.y = fmaxf(acc.y + bv.y, 0.f);
        acc.z = fmaxf(acc.z + bv.z, 0.f);
        acc.w = fmaxf(acc.w + bv.w, 0.f);
        ((float4*)(x1 + (size_t)i * D1))[lane & 31] = acc;
    }
}

// h2 = x1 @ W2, written IN-PLACE into x1 row cols 0..63.
// Block = 16 consecutive rows (4 waves x 4 rows). W2 in LDS [k][j] (row reads
// by 64 consecutive lanes are conflict-free). unroll 4 keeps VGPR low.
__global__ __launch_bounds__(256) void gemm2_k(float* __restrict__ x1,
                                               const float* __restrict__ W2, int n) {
    __shared__ float w[D1 * D2];  // 32 KB
    for (int t = threadIdx.x; t < D1 * D2; t += 256) w[t] = W2[t];
    __syncthreads();
    int wib = threadIdx.x >> 6;   // 0..3
    int lane = threadIdx.x & 63;
    int r0 = blockIdx.x * 16 + wib * 4;
    for (int rr = 0; rr < 4; ++rr) {
        int r = r0 + rr;
        if (r >= n) break;
        const float4* xr = (const float4*)(x1 + (size_t)r * D1);
        float a0 = 0.f, a1 = 0.f, a2 = 0.f, a3 = 0.f;
        #pragma unroll 4
        for (int k4 = 0; k4 < D1 / 4; ++k4) {
            float4 xv = xr[k4];
            a0 = fmaf(xv.x, w[(k4 * 4 + 0) * D2 + lane], a0);
            a1 = fmaf(xv.y, w[(k4 * 4 + 1) * D2 + lane], a1);
            a2 = fmaf(xv.z, w[(k4 * 4 + 2) * D2 + lane], a2);
            a3 = fmaf(xv.w, w[(k4 * 4 + 3) * D2 + lane], a3);
        }
        x1[(size_t)r * D1 + lane] = (a0 + a1) + (a2 + a3);  // h2 row, in-place
    }
}

// layer-2 aggregation: ONE WAVE PER NODE. 4 sub-groups of 16 lanes; each sub
// handles one edge per iteration, lane holds float4 at feature (lane&15)*4.
// h2 rows live at x1 + s*D1 (cols 0..63).
__global__ __launch_bounds__(256) void agg2_k(const int* __restrict__ csr_src,
                                              const float* __restrict__ csr_dis,
                                              const int* __restrict__ off,
                                              const int* __restrict__ cnt,
                                              const float* __restrict__ dis,
                                              const float* __restrict__ h2,
                                              const float* __restrict__ b2,
                                              float* __restrict__ out, int n) {
    int i = (blockIdx.x * blockDim.x + threadIdx.x) >> 6;   // node = wave id
    if (i >= n) return;
    int lane = threadIdx.x & 63;
    int sub = lane >> 4;            // 0..3
    int fl = (lane & 15) << 2;      // feature base 0..60
    float disi = dis[i];
    int base = off[i], c = cnt[i];
    int total = c + 1;              // + self loop (virtual edge idx==c)
    float4 acc = make_float4(0.f, 0.f, 0.f, 0.f);
    for (int cb = 0; cb < total; cb += 64) {
        int idx = cb + lane;
        int s_l = i;
        float c_l = 0.f;
        if (idx < c) {
            s_l = csr_src[base + idx];
            c_l = disi * csr_dis[base + idx];
        } else if (idx == c) {
            c_l = disi * disi;      // self loop
        }
        int m = min(64, total - cb);
        for (int k0 = 0; k0 < m; k0 += 4) {
            int k = k0 + sub;       // <= 63 always
            int s = __shfl(s_l, k);
            float cf = __shfl(c_l, k);  // 0 for out-of-range k
            float4 v = *(const float4*)(h2 + (size_t)s * D1 + fl);
            acc.x = fmaf(v.x, cf, acc.x);
            acc.y = fmaf(v.y, cf, acc.y);
            acc.z = fmaf(v.z, cf, acc.z);
            acc.w = fmaf(v.w, cf, acc.w);
        }
    }
    // reduce the four sub-groups
    acc.x += __shfl_xor(acc.x, 16);
    acc.y += __shfl_xor(acc.y, 16);
    acc.z += __shfl_xor(acc.z, 16);
    acc.w += __shfl_xor(acc.w, 16);
    acc.x += __shfl_xor(acc.x, 32);
    acc.y += __shfl_xor(acc.y, 32);
    acc.z += __shfl_xor(acc.z, 32);
    acc.w += __shfl_xor(acc.w, 32);
    if (sub == 0) {
        float4 bv = ((const float4*)b2)[lane & 15];
        acc.x += bv.x;
        acc.y += bv.y;
        acc.z += bv.z;
        acc.w += bv.w;
        ((float4*)(out + (size_t)i * D2))[lane & 15] = acc;
    }
}

extern "C" void kernel_launch(void* const* d_in, const int* in_sizes, int n_in,
                              void* d_out, int out_size, void* d_ws, size_t ws_size,
                              hipStream_t stream) {
    const int* types = (const int*)d_in[0];
    const int* edges = (const int*)d_in[1];
    const float* emb = (const float*)d_in[2];
    const float* W1  = (const float*)d_in[3];
    const float* b1  = (const float*)d_in[4];
    const float* W2  = (const float*)d_in[5];
    const float* b2  = (const float*)d_in[6];
    float* out = (float*)d_out;

    const int n = in_sizes[0];
    const int e = in_sizes[1] / 2;
    const int ntypes = in_sizes[2] / D1;
    const int* src = edges;
    const int* dst = edges + e;

    // ---- workspace layout (256B aligned slabs), ~72.5 MB total ----
    char* p = (char*)d_ws;
    auto alloc = [&](size_t bytes) {
        char* r = p;
        p += (bytes + 255) & ~(size_t)255;
        return r;
    };
    int*   off      = (int*)  alloc((size_t)(n + 1) * 4);
    int*   cnt      = (int*)  alloc((size_t)n * 4);
    int*   cursor   = (int*)  alloc((size_t)n * 4);
    int*   bsum     = (int*)  alloc(1024 * 4);
    float* dis      = (float*)alloc((size_t)n * 4);
    int*   csr_src  = (int*)  alloc((size_t)e * 4);
    int*   csr_type = (int*)  alloc((size_t)e * 4);
    float* csr_dis  = (float*)alloc((size_t)e * 4);
    float* embW     = (float*)alloc((size_t)ntypes * D1 * 4);
    float* x1       = (float*)alloc((size_t)n * D1 * 4);  // also holds h2 in cols 0..63
    (void)ws_size;

    hipMemsetAsync(cnt, 0, (size_t)n * 4, stream);
    hipMemsetAsync(cursor, 0, (size_t)n * 4, stream);

    // ---- degree / dis / CSR (+ per-edge type/dis payloads) ----
    count_k<<<2048, 256, 0, stream>>>(dst, cnt, e);
    dis_k<<<(n + 255) / 256, 256, 0, stream>>>(cnt, dis, n);
    int nb = (n + 255) / 256;   // 391 for N=100000 (must be <= 1024)
    scan1_k<<<nb, 256, 0, stream>>>(cnt, off, bsum, n);
    scan2_k<<<1, 1024, 0, stream>>>(bsum, nb);
    scan3_k<<<nb, 256, 0, stream>>>(off, bsum, n);
    fill_k<<<2048, 256, 0, stream>>>(src, dst, types, dis, off, cursor,
                                     csr_src, csr_type, csr_dis, e);

    // ---- layer 1: embW = emb@W1; aggregate -> x1 (relu(agg + b1)) ----
    gemm_emb_k<<<256, 128, 0, stream>>>(emb, W1, embW, ntypes);
    int nwb = (n + 3) / 4;      // one wave per node, 4 waves per block
    agg1_k<<<nwb, 256, 0, stream>>>(types, csr_type, csr_dis, off, cnt, dis,
                                    embW, b1, x1, n);

    // ---- layer 2: h2 = x1@W2 in-place; aggregate h2 -> out ----
    gemm2_k<<<(n + 15) / 16, 256, 0, stream>>>(x1, W2, n);
    agg2_k<<<nwb, 256, 0, stream>>>(csr_src, csr_dis, off, cnt, dis,
                                    x1, b2, out, n);
}